// Round 4
// baseline (221.429 us; speedup 1.0000x reference)
//
#include <hip/hip_runtime.h>
#include <stdint.h>

typedef __attribute__((ext_vector_type(8))) __bf16 bf16x8;
typedef __attribute__((ext_vector_type(4))) float f32x4;

template <int V> struct ic { static constexpr int value = V; };

// ---- fp32 -> bf16 (RNE) ----
__device__ __forceinline__ unsigned short f2bf(float f) {
    unsigned u = __float_as_uint(f);
    u += 0x7FFF + ((u >> 16) & 1);
    return (unsigned short)(u >> 16);
}

__global__ __launch_bounds__(256)
void f32_to_bf16_k(const float* __restrict__ in, unsigned short* __restrict__ out, int n4) {
    int i = blockIdx.x * blockDim.x + threadIdx.x;
    int stride = gridDim.x * blockDim.x;
    for (; i < n4; i += stride) {
        float4 v = reinterpret_cast<const float4*>(in)[i];
        ushort4 o;
        o.x = f2bf(v.x); o.y = f2bf(v.y); o.z = f2bf(v.z); o.w = f2bf(v.w);
        reinterpret_cast<ushort4*>(out)[i] = o;
    }
}

__global__ __launch_bounds__(256)
void w_convert_k(const float* __restrict__ Wq, const float* __restrict__ Wk,
                 const float* __restrict__ Wv, unsigned short* __restrict__ out, int n4) {
    const float* src = blockIdx.y == 0 ? Wq : (blockIdx.y == 1 ? Wk : Wv);
    unsigned short* dst = out + (size_t)blockIdx.y * n4 * 4;
    int i = blockIdx.x * blockDim.x + threadIdx.x;
    int stride = gridDim.x * blockDim.x;
    for (; i < n4; i += stride) {
        float4 v = reinterpret_cast<const float4*>(src)[i];
        ushort4 o;
        o.x = f2bf(v.x); o.y = f2bf(v.y); o.z = f2bf(v.z); o.w = f2bf(v.w);
        reinterpret_cast<ushort4*>(dst)[i] = o;
    }
}

__device__ __forceinline__ void gload16(const unsigned short* g, unsigned short* l) {
    __builtin_amdgcn_global_load_lds(
        (const __attribute__((address_space(1))) unsigned int*)g,
        (__attribute__((address_space(3))) unsigned int*)l, 16, 0, 0);
}

// ============ 4-phase-per-K-tile pipelined NT GEMM (BK=64, 512 thr) ============
// C[m,n] = scale * sum_k A[m,k]*B[n,k];  A:[M,K], B:[N,K] row-major bf16.
// LDS [rows][64]bf16; 16B chunk cc of row stored at chunk (cc ^ (row&7)) -- applied
// on the GLOBAL source address (LDS dest linear for global_load_lds) and again on
// the ds_read address (involution). Double-buffered per K-tile.
// Per K-tile: 4 phases; phase p = {stage part of next tile || ds_read quadrant frags;
// s_barrier; lgkmcnt(0); setprio(1); (FM/2*FN/2*2) MFMA; setprio(0); s_barrier}.
// One vmcnt(0) per tile after p3's MFMA (staged loads have ~2.5 phases of cover).
template <int BM, int BN, int WM, int WN, typename CT, bool TRI, bool KLIM>
__global__ __launch_bounds__(512, 2)
void gemm8(const unsigned short* __restrict__ A, const unsigned short* __restrict__ B,
           CT* __restrict__ C, int lda, int ldb, int ldc, int K,
           long long sA, long long sB, long long sC, float scale)
{
    constexpr int FM = BM / WM / 16;             // M-frags per wave (8)
    constexpr int FN = BN / WN / 16;             // N-frags per wave (4 or 2)
    static_assert(FM % 2 == 0 && FN % 2 == 0, "");

    int br = blockIdx.y, bc = blockIdx.x;
    if (TRI && bc > br) return;
    A += (long long)blockIdx.z * sA;
    B += (long long)blockIdx.z * sB;
    C += (long long)blockIdx.z * sC;

    int kmax = K;
    if (KLIM) { int kl = (br + 1) * BM; kmax = kl < K ? kl : K; }

    __shared__ unsigned short As[2][BM * 64];
    __shared__ unsigned short Bs[2][BN * 64];

    const int t    = threadIdx.x;
    const int lane = t & 63;
    const int wid  = t >> 6;
    const int wm   = wid / WN;
    const int wn   = wid % WN;
    const int m0   = br * BM, n0 = bc * BN;
    const int rsel = lane & 15;
    const int gsel = lane >> 4;                  // 0..3

    f32x4 acc[FM][FN];
#pragma unroll
    for (int m = 0; m < FM; ++m)
#pragma unroll
        for (int n = 0; n < FN; ++n) acc[m][n] = (f32x4){0.f, 0.f, 0.f, 0.f};

    auto stageA = [&](int buf, int kt) {
        const int k0 = kt * 64;
#pragma unroll
        for (int i = 0; i < BM / 64; ++i) {
            int ci = i * 512 + t;
            int row = ci >> 3, cc = ci & 7;
            gload16(A + (long long)(m0 + row) * lda + k0 + ((cc ^ (row & 7)) * 8),
                    &As[buf][ci * 8]);
        }
    };
    auto stageB = [&](int buf, int kt) {
        const int k0 = kt * 64;
#pragma unroll
        for (int i = 0; i < BN / 64; ++i) {
            int ci = i * 512 + t;
            int row = ci >> 3, cc = ci & 7;
            gload16(B + (long long)(n0 + row) * ldb + k0 + ((cc ^ (row & 7)) * 8),
                    &Bs[buf][ci * 8]);
        }
    };

    auto readA = [&](int c, int qm, bf16x8 (&dst)[FM / 2][2]) {
#pragma unroll
        for (int mm = 0; mm < FM / 2; ++mm)
#pragma unroll
            for (int ks = 0; ks < 2; ++ks) {
                int r  = wm * (FM * 16) + (qm * (FM / 2) + mm) * 16 + rsel;
                int cc = ks * 4 + gsel;
                dst[mm][ks] = *reinterpret_cast<const bf16x8*>(
                    &As[c][r * 64 + ((cc ^ (r & 7)) * 8)]);
            }
    };
    auto readB = [&](int c, int qn, bf16x8 (&dst)[FN / 2][2]) {
#pragma unroll
        for (int nn = 0; nn < FN / 2; ++nn)
#pragma unroll
            for (int ks = 0; ks < 2; ++ks) {
                int rb = wn * (FN * 16) + (qn * (FN / 2) + nn) * 16 + rsel;
                int cc = ks * 4 + gsel;
                dst[nn][ks] = *reinterpret_cast<const bf16x8*>(
                    &Bs[c][rb * 64 + ((cc ^ (rb & 7)) * 8)]);
            }
    };

    auto mfmaQ = [&](auto QM, auto QN, bf16x8 (&aF)[FM / 2][2], bf16x8 (&bF)[FN / 2][2]) {
        constexpr int qm = decltype(QM)::value, qn = decltype(QN)::value;
        __builtin_amdgcn_s_setprio(1);
#pragma unroll
        for (int mm = 0; mm < FM / 2; ++mm)
#pragma unroll
            for (int nn = 0; nn < FN / 2; ++nn)
#pragma unroll
                for (int ks = 0; ks < 2; ++ks)
                    acc[qm * (FM / 2) + mm][qn * (FN / 2) + nn] =
                        __builtin_amdgcn_mfma_f32_16x16x32_bf16(
                            aF[mm][ks], bF[nn][ks],
                            acc[qm * (FM / 2) + mm][qn * (FN / 2) + nn], 0, 0, 0);
        __builtin_amdgcn_s_setprio(0);
    };

#define BARRIER_FENCE() do { __builtin_amdgcn_s_barrier(); asm volatile("" ::: "memory"); } while (0)
#define LGKM0_PIN()     do { asm volatile("s_waitcnt lgkmcnt(0)" ::: "memory"); \
                             __builtin_amdgcn_sched_barrier(0); } while (0)

    const int nk = kmax >> 6;
    stageA(0, 0); stageB(0, 0);
    asm volatile("s_waitcnt vmcnt(0)" ::: "memory");
    BARRIER_FENCE();

    bf16x8 aF[FM / 2][2], bF0[FN / 2][2], bF1[FN / 2][2];

    for (int kt = 0; kt < nk; ++kt) {
        const int c = kt & 1;
        const bool pf = (kt + 1 < nk);
        // phase 0: stage A(next) || read A0,B0 -> mfma(0,0)
        if (pf) stageA(c ^ 1, kt + 1);
        readA(c, 0, aF);
        readB(c, 0, bF0);
        __builtin_amdgcn_s_barrier();
        LGKM0_PIN();
        mfmaQ(ic<0>{}, ic<0>{}, aF, bF0);
        BARRIER_FENCE();
        // phase 1: stage B(next) || read B1 -> mfma(0,1)
        if (pf) stageB(c ^ 1, kt + 1);
        readB(c, 1, bF1);
        __builtin_amdgcn_s_barrier();
        LGKM0_PIN();
        mfmaQ(ic<0>{}, ic<1>{}, aF, bF1);
        BARRIER_FENCE();
        // phase 2: read A1 -> mfma(1,0)
        readA(c, 1, aF);
        __builtin_amdgcn_s_barrier();
        LGKM0_PIN();
        mfmaQ(ic<1>{}, ic<0>{}, aF, bF0);
        BARRIER_FENCE();
        // phase 3: mfma(1,1); drain next-tile staging (cover ~2.5 phases)
        mfmaQ(ic<1>{}, ic<1>{}, aF, bF1);
        asm volatile("s_waitcnt vmcnt(0)" ::: "memory");
        BARRIER_FENCE();
    }
#undef BARRIER_FENCE
#undef LGKM0_PIN

    // epilogue: D[row][col], col = lane&15, row = (lane>>4)*4 + i  (m89-verified)
    const int rowl = (lane >> 4) * 4;
#pragma unroll
    for (int m = 0; m < FM; ++m) {
#pragma unroll
        for (int n = 0; n < FN; ++n) {
#pragma unroll
            for (int i = 0; i < 4; ++i) {
                int r  = m0 + wm * (FM * 16) + m * 16 + rowl + i;
                int cI = n0 + wn * (FN * 16) + n * 16 + rsel;
                float v = acc[m][n][i] * scale;
                if constexpr (sizeof(CT) == 2)
                    ((unsigned short*)C)[(long long)r * ldc + cI] = f2bf(v);
                else
                    ((float*)C)[(long long)r * ldc + cI] = v;
            }
        }
    }
}

// ---- causal row softmax: 1 global read (LDS-cached), vectorized ----
__device__ __forceinline__ float waveMax(float v) {
#pragma unroll
    for (int o = 32; o > 0; o >>= 1) v = fmaxf(v, __shfl_xor(v, o, 64));
    return v;
}
__device__ __forceinline__ float waveSum(float v) {
#pragma unroll
    for (int o = 32; o > 0; o >>= 1) v += __shfl_xor(v, o, 64);
    return v;
}

__global__ __launch_bounds__(256)
void softmax_causal(const float* __restrict__ S, unsigned short* __restrict__ P, int Slen) {
    __shared__ float e[2048];
    __shared__ float red[4];
    long long row = blockIdx.x;                 // b*Slen + q
    int q = (int)(row % Slen);
    const float* srow = S + row * (long long)Slen;
    unsigned short* prow = P + row * (long long)Slen;
    int len = q + 1;
    int t = threadIdx.x;

    int nfull = len >> 2;
    float mx = -3.0e38f;
    for (int i = t; i < nfull; i += 256) {
        float4 v = reinterpret_cast<const float4*>(srow)[i];
        e[4 * i + 0] = v.x; e[4 * i + 1] = v.y;
        e[4 * i + 2] = v.z; e[4 * i + 3] = v.w;
        mx = fmaxf(fmaxf(fmaxf(mx, v.x), v.y), fmaxf(v.z, v.w));
    }
    if (t < (len & 3)) {
        float v = srow[nfull * 4 + t];
        e[nfull * 4 + t] = v;
        mx = fmaxf(mx, v);
    }
    mx = waveMax(mx);
    if ((t & 63) == 0) red[t >> 6] = mx;
    __syncthreads();
    mx = fmaxf(fmaxf(red[0], red[1]), fmaxf(red[2], red[3]));

    float sum = 0.f;
    for (int k = t; k < len; k += 256) {
        float v = __expf(e[k] - mx);
        e[k] = v;
        sum += v;
    }
    sum = waveSum(sum);
    __syncthreads();
    if ((t & 63) == 0) red[t >> 6] = sum;
    __syncthreads();
    sum = red[0] + red[1] + red[2] + red[3];
    float inv = 1.0f / sum;

    int wlim = ((q >> 7) + 1) << 7;             // PV reads only k < roundup(len,128)
    __syncthreads();                            // e[] writes visible
    for (int i = t; i < (wlim >> 2); i += 256) {
        int k = 4 * i;
        ushort4 o;
        o.x = (k + 0 < len) ? f2bf(e[k + 0] * inv) : (unsigned short)0;
        o.y = (k + 1 < len) ? f2bf(e[k + 1] * inv) : (unsigned short)0;
        o.z = (k + 2 < len) ? f2bf(e[k + 2] * inv) : (unsigned short)0;
        o.w = (k + 3 < len) ? f2bf(e[k + 3] * inv) : (unsigned short)0;
        reinterpret_cast<ushort4*>(prow)[i] = o;
    }
}

extern "C" void kernel_launch(void* const* d_in, const int* in_sizes, int n_in,
                              void* d_out, int out_size, void* d_ws, size_t ws_size,
                              hipStream_t stream) {
    const int B = 4, S = 2048, D = 1024;
    const float* X  = (const float*)d_in[0];
    const float* Wq = (const float*)d_in[1];
    const float* Wk = (const float*)d_in[2];
    const float* Wv = (const float*)d_in[3];
    float* out = (float*)d_out;

    char* ws = (char*)d_ws;
    unsigned short* Xb  = (unsigned short*)ws; ws += (size_t)B * S * D * 2;
    unsigned short* Wqb = (unsigned short*)ws; ws += (size_t)D * D * 2;  // Wq,Wk,Wv contiguous
    unsigned short* Wkb = (unsigned short*)ws; ws += (size_t)D * D * 2;
    unsigned short* Wvb = (unsigned short*)ws; ws += (size_t)D * D * 2;
    unsigned short* Qb  = (unsigned short*)ws; ws += (size_t)B * S * D * 2;  // Q,K contiguous
    unsigned short* Kb  = (unsigned short*)ws; ws += (size_t)B * S * D * 2;
    unsigned short* Vt  = (unsigned short*)ws; ws += (size_t)B * S * D * 2;  // [b][e][k]
    float*          Sc  = (float*)ws;          ws += (size_t)B * S * S * 4;
    unsigned short* P   = (unsigned short*)ws; ws += (size_t)B * S * S * 2;

    f32_to_bf16_k<<<2048, 256, 0, stream>>>(X, Xb, B * S * D / 4);
    w_convert_k<<<dim3(512, 3), 256, 0, stream>>>(Wq, Wk, Wv, Wqb, D * D / 4);

    dim3 blk(512);
    // Q and K in one dispatch: 256x256 tiles, grid (4, 32, 2) = 256 blocks
    gemm8<256, 256, 2, 4, unsigned short, false, false>
        <<<dim3(D / 256, B * S / 256, 2), blk, 0, stream>>>(
        Xb, Wqb, Qb, D, D, D, D, 0, (long long)D * D, (long long)B * S * D, 1.0f);

    // Vt[b] = Wv @ Xb[b]^T : 128x256 tiles, grid (8, 8, 4) = 256 blocks
    gemm8<128, 256, 1, 8, unsigned short, false, false>
        <<<dim3(S / 256, D / 128, B), blk, 0, stream>>>(
        Wvb, Xb, Vt, D, D, S, D, 0, (long long)S * D, (long long)D * S, 1.0f);

    // scores = (Q K^T)/32, lower-triangle 256x256 blocks, fp32: grid (8,8,4), TRI
    gemm8<256, 256, 2, 4, float, true, false>
        <<<dim3(S / 256, S / 256, B), blk, 0, stream>>>(
        Qb, Kb, Sc, D, D, S, D, (long long)S * D, (long long)S * D, (long long)S * S, 0.03125f);

    softmax_causal<<<B * S, 256, 0, stream>>>(Sc, P, S);

    // out = P @ Vt^T : 128x256 tiles, grid (4, 16, 4) = 256 blocks, KLIM
    gemm8<128, 256, 1, 8, float, false, true>
        <<<dim3(D / 256, S / 128, B), blk, 0, stream>>>(
        P, Vt, out, S, S, D, S, (long long)S * S, (long long)D * S, (long long)S * D, 1.0f);
}

// Round 5
// 181.739 us; speedup vs baseline: 1.2184x; 1.2184x over previous
//
#include <hip/hip_runtime.h>
#include <stdint.h>

typedef __attribute__((ext_vector_type(8))) __bf16 bf16x8;
typedef __attribute__((ext_vector_type(4))) float f32x4;

// ---- fp32 -> bf16 (RNE) ----
__device__ __forceinline__ unsigned short f2bf(float f) {
    unsigned u = __float_as_uint(f);
    u += 0x7FFF + ((u >> 16) & 1);
    return (unsigned short)(u >> 16);
}

__global__ __launch_bounds__(256)
void f32_to_bf16_k(const float* __restrict__ in, unsigned short* __restrict__ out, int n4) {
    int i = blockIdx.x * blockDim.x + threadIdx.x;
    int stride = gridDim.x * blockDim.x;
    for (; i < n4; i += stride) {
        float4 v = reinterpret_cast<const float4*>(in)[i];
        ushort4 o;
        o.x = f2bf(v.x); o.y = f2bf(v.y); o.z = f2bf(v.z); o.w = f2bf(v.w);
        reinterpret_cast<ushort4*>(out)[i] = o;
    }
}

__global__ __launch_bounds__(256)
void w_convert_k(const float* __restrict__ Wq, const float* __restrict__ Wk,
                 const float* __restrict__ Wv, unsigned short* __restrict__ out, int n4) {
    const float* src = blockIdx.y == 0 ? Wq : (blockIdx.y == 1 ? Wk : Wv);
    unsigned short* dst = out + (size_t)blockIdx.y * n4 * 4;
    int i = blockIdx.x * blockDim.x + threadIdx.x;
    int stride = gridDim.x * blockDim.x;
    for (; i < n4; i += stride) {
        float4 v = reinterpret_cast<const float4*>(src)[i];
        ushort4 o;
        o.x = f2bf(v.x); o.y = f2bf(v.y); o.z = f2bf(v.z); o.w = f2bf(v.w);
        reinterpret_cast<ushort4*>(dst)[i] = o;
    }
}

__device__ __forceinline__ void gload16(const unsigned short* g, unsigned short* l) {
    __builtin_amdgcn_global_load_lds(
        (const __attribute__((address_space(1))) unsigned int*)g,
        (__attribute__((address_space(3))) unsigned int*)l, 16, 0, 0);
}

// ============ NT GEMM core: BK=64, counted-vmcnt double buffer, XOR swizzle ============
// 128x128 tile, 256 threads (4 waves 2x2), LDS 64KB -> 2 blocks/CU.
// C[m,n] = scale * sum_k A[m,k]*B[n,k];  A:[M,K], B:[N,K] row-major bf16.
// LDS [rows][64]bf16; 16B chunk cc of row stored at chunk (cc ^ (row&7)): applied on the
// GLOBAL source address (LDS dest linear for global_load_lds) and on the ds_read address.
// vmcnt chain: each iter issues LPT=8 loads for tile t+1, waits vmcnt(8) -> all of tile t's
// loads (issued last iter, one full tile of cover) drained; tile t+1's stay in flight.
template <int BM, int BN, int WM, int WN, typename CT, bool TRI, bool KLIM>
__global__ __launch_bounds__(256, 2)
void gemm8(const unsigned short* __restrict__ A, const unsigned short* __restrict__ B,
           CT* __restrict__ C, int lda, int ldb, int ldc, int K,
           long long sA, long long sB, long long sC, float scale)
{
    constexpr int FM  = BM / WM / 16;            // 4
    constexpr int FN  = BN / WN / 16;            // 4
    constexpr int ACH = BM * 8;                  // A 16B-chunks per tile
    constexpr int LPT = (BM + BN) * 8 / 256;     // 8 loads/thread/tile

    int br = blockIdx.y, bc = blockIdx.x;
    if (TRI && bc > br) return;
    A += (long long)blockIdx.z * sA;
    B += (long long)blockIdx.z * sB;
    C += (long long)blockIdx.z * sC;

    int kmax = K;
    if (KLIM) { int kl = (br + 1) * BM; kmax = kl < K ? kl : K; }

    __shared__ unsigned short As[2][BM * 64];
    __shared__ unsigned short Bs[2][BN * 64];

    const int t    = threadIdx.x;
    const int lane = t & 63;
    const int wid  = t >> 6;
    const int wm   = wid / WN;
    const int wn   = wid % WN;
    const int m0   = br * BM, n0 = bc * BN;
    const int rsel = lane & 15;
    const int gsel = lane >> 4;                  // 0..3

    f32x4 acc[FM][FN];
#pragma unroll
    for (int m = 0; m < FM; ++m)
#pragma unroll
        for (int n = 0; n < FN; ++n) acc[m][n] = (f32x4){0.f, 0.f, 0.f, 0.f};

    auto stage = [&](int buf, int kt) {
        const int k0 = kt * 64;
#pragma unroll
        for (int i = 0; i < LPT; ++i) {
            int ci = i * 256 + t;
            if (ci < ACH) {
                int row = ci >> 3, cc = ci & 7;
                gload16(A + (long long)(m0 + row) * lda + k0 + ((cc ^ (row & 7)) * 8),
                        &As[buf][ci * 8]);
            } else {
                int cj = ci - ACH;
                int row = cj >> 3, cc = cj & 7;
                gload16(B + (long long)(n0 + row) * ldb + k0 + ((cc ^ (row & 7)) * 8),
                        &Bs[buf][cj * 8]);
            }
        }
    };

    const int nk = kmax >> 6;
    stage(0, 0);

    for (int kt = 0; kt < nk; ++kt) {
        const int c = kt & 1;
        // previous compute done -> safe to overwrite buf c^1
        __builtin_amdgcn_s_barrier();
        __builtin_amdgcn_sched_barrier(0);
        if (kt + 1 < nk) {
            stage(c ^ 1, kt + 1);                // tile t+1 loads stay in flight
            asm volatile("s_waitcnt vmcnt(8)" ::: "memory");  // tile t fully landed
        } else {
            asm volatile("s_waitcnt vmcnt(0)" ::: "memory");
        }
        __builtin_amdgcn_s_barrier();            // collective guarantee for buf c
        __builtin_amdgcn_sched_barrier(0);

        bf16x8 aF[FM][2], bF[FN][2];
#pragma unroll
        for (int m = 0; m < FM; ++m)
#pragma unroll
            for (int ks = 0; ks < 2; ++ks) {
                int r  = wm * (FM * 16) + m * 16 + rsel;
                int cc = ks * 4 + gsel;
                aF[m][ks] = *reinterpret_cast<const bf16x8*>(
                    &As[c][r * 64 + ((cc ^ (r & 7)) * 8)]);
            }
#pragma unroll
        for (int n = 0; n < FN; ++n)
#pragma unroll
            for (int ks = 0; ks < 2; ++ks) {
                int rb = wn * (FN * 16) + n * 16 + rsel;
                int cc = ks * 4 + gsel;
                bF[n][ks] = *reinterpret_cast<const bf16x8*>(
                    &Bs[c][rb * 64 + ((cc ^ (rb & 7)) * 8)]);
            }

        __builtin_amdgcn_s_setprio(1);
#pragma unroll
        for (int m = 0; m < FM; ++m)
#pragma unroll
            for (int n = 0; n < FN; ++n)
#pragma unroll
                for (int ks = 0; ks < 2; ++ks)
                    acc[m][n] = __builtin_amdgcn_mfma_f32_16x16x32_bf16(
                        aF[m][ks], bF[n][ks], acc[m][n], 0, 0, 0);
        __builtin_amdgcn_s_setprio(0);
    }

    // epilogue: D[row][col], col = lane&15, row = (lane>>4)*4 + i  (m89-verified)
    const int rowl = (lane >> 4) * 4;
#pragma unroll
    for (int m = 0; m < FM; ++m) {
#pragma unroll
        for (int n = 0; n < FN; ++n) {
#pragma unroll
            for (int i = 0; i < 4; ++i) {
                int r  = m0 + wm * (FM * 16) + m * 16 + rowl + i;
                int cI = n0 + wn * (FN * 16) + n * 16 + rsel;
                float v = acc[m][n][i] * scale;
                if constexpr (sizeof(CT) == 2)
                    ((unsigned short*)C)[(long long)r * ldc + cI] = f2bf(v);
                else
                    ((float*)C)[(long long)r * ldc + cI] = v;
            }
        }
    }
}

// ---- causal row softmax: 1 global read (LDS-cached), vectorized ----
__device__ __forceinline__ float waveMax(float v) {
#pragma unroll
    for (int o = 32; o > 0; o >>= 1) v = fmaxf(v, __shfl_xor(v, o, 64));
    return v;
}
__device__ __forceinline__ float waveSum(float v) {
#pragma unroll
    for (int o = 32; o > 0; o >>= 1) v += __shfl_xor(v, o, 64);
    return v;
}

__global__ __launch_bounds__(256)
void softmax_causal(const float* __restrict__ S, unsigned short* __restrict__ P, int Slen) {
    __shared__ float e[2048];
    __shared__ float red[4];
    long long row = blockIdx.x;                 // b*Slen + q
    int q = (int)(row % Slen);
    const float* srow = S + row * (long long)Slen;
    unsigned short* prow = P + row * (long long)Slen;
    int len = q + 1;
    int t = threadIdx.x;

    int nfull = len >> 2;
    float mx = -3.0e38f;
    for (int i = t; i < nfull; i += 256) {
        float4 v = reinterpret_cast<const float4*>(srow)[i];
        e[4 * i + 0] = v.x; e[4 * i + 1] = v.y;
        e[4 * i + 2] = v.z; e[4 * i + 3] = v.w;
        mx = fmaxf(fmaxf(fmaxf(mx, v.x), v.y), fmaxf(v.z, v.w));
    }
    if (t < (len & 3)) {
        float v = srow[nfull * 4 + t];
        e[nfull * 4 + t] = v;
        mx = fmaxf(mx, v);
    }
    mx = waveMax(mx);
    if ((t & 63) == 0) red[t >> 6] = mx;
    __syncthreads();
    mx = fmaxf(fmaxf(red[0], red[1]), fmaxf(red[2], red[3]));

    float sum = 0.f;
    for (int k = t; k < len; k += 256) {
        float v = __expf(e[k] - mx);
        e[k] = v;
        sum += v;
    }
    sum = waveSum(sum);
    __syncthreads();
    if ((t & 63) == 0) red[t >> 6] = sum;
    __syncthreads();
    sum = red[0] + red[1] + red[2] + red[3];
    float inv = 1.0f / sum;

    int wlim = ((q >> 7) + 1) << 7;             // PV (BM=128) reads only k < roundup(len,128)
    __syncthreads();                            // e[] writes visible
    for (int i = t; i < (wlim >> 2); i += 256) {
        int k = 4 * i;
        ushort4 o;
        o.x = (k + 0 < len) ? f2bf(e[k + 0] * inv) : (unsigned short)0;
        o.y = (k + 1 < len) ? f2bf(e[k + 1] * inv) : (unsigned short)0;
        o.z = (k + 2 < len) ? f2bf(e[k + 2] * inv) : (unsigned short)0;
        o.w = (k + 3 < len) ? f2bf(e[k + 3] * inv) : (unsigned short)0;
        reinterpret_cast<ushort4*>(prow)[i] = o;
    }
}

extern "C" void kernel_launch(void* const* d_in, const int* in_sizes, int n_in,
                              void* d_out, int out_size, void* d_ws, size_t ws_size,
                              hipStream_t stream) {
    const int B = 4, S = 2048, D = 1024;
    const float* X  = (const float*)d_in[0];
    const float* Wq = (const float*)d_in[1];
    const float* Wk = (const float*)d_in[2];
    const float* Wv = (const float*)d_in[3];
    float* out = (float*)d_out;

    char* ws = (char*)d_ws;
    unsigned short* Xb  = (unsigned short*)ws; ws += (size_t)B * S * D * 2;
    unsigned short* Wqb = (unsigned short*)ws; ws += (size_t)D * D * 2;  // Wq,Wk,Wv contiguous
    unsigned short* Wkb = (unsigned short*)ws; ws += (size_t)D * D * 2;
    unsigned short* Wvb = (unsigned short*)ws; ws += (size_t)D * D * 2;
    unsigned short* Qb  = (unsigned short*)ws; ws += (size_t)B * S * D * 2;  // Q,K contiguous
    unsigned short* Kb  = (unsigned short*)ws; ws += (size_t)B * S * D * 2;
    unsigned short* Vt  = (unsigned short*)ws; ws += (size_t)B * S * D * 2;  // [b][e][k]
    float*          Sc  = (float*)ws;          ws += (size_t)B * S * S * 4;
    unsigned short* P   = (unsigned short*)ws; ws += (size_t)B * S * S * 2;

    f32_to_bf16_k<<<2048, 256, 0, stream>>>(X, Xb, B * S * D / 4);
    w_convert_k<<<dim3(512, 3), 256, 0, stream>>>(Wq, Wk, Wv, Wqb, D * D / 4);

    dim3 blk(256);
    // Q and K in one dispatch: 128x128 tiles, grid (8, 64, 2) = 1024 blocks (2 resident/CU)
    gemm8<128, 128, 2, 2, unsigned short, false, false>
        <<<dim3(D / 128, B * S / 128, 2), blk, 0, stream>>>(
        Xb, Wqb, Qb, D, D, D, D, 0, (long long)D * D, (long long)B * S * D, 1.0f);

    // Vt[b] = Wv @ Xb[b]^T : grid (16, 8, 4) = 512 blocks
    gemm8<128, 128, 2, 2, unsigned short, false, false>
        <<<dim3(S / 128, D / 128, B), blk, 0, stream>>>(
        Wvb, Xb, Vt, D, D, S, D, 0, (long long)S * D, (long long)D * S, 1.0f);

    // scores = (Q K^T)/32, lower-triangle blocks, fp32: grid (16,16,4), TRI
    gemm8<128, 128, 2, 2, float, true, false>
        <<<dim3(S / 128, S / 128, B), blk, 0, stream>>>(
        Qb, Kb, Sc, D, D, S, D, (long long)S * D, (long long)S * D, (long long)S * S, 0.03125f);

    softmax_causal<<<B * S, 256, 0, stream>>>(Sc, P, S);

    // out = P @ Vt^T : grid (8, 16, 4) = 512 blocks, KLIM
    gemm8<128, 128, 2, 2, float, false, true>
        <<<dim3(D / 128, S / 128, B), blk, 0, stream>>>(
        P, Vt, out, S, S, D, S, (long long)S * S, (long long)D * S, (long long)S * D, 1.0f);
}

// Round 6
// 175.027 us; speedup vs baseline: 1.2651x; 1.0383x over previous
//
#include <hip/hip_runtime.h>
#include <stdint.h>
#include <math.h>

typedef __attribute__((ext_vector_type(8))) __bf16 bf16x8;
typedef __attribute__((ext_vector_type(4))) float f32x4;

// ---- fp32 -> bf16 (RNE) ----
__device__ __forceinline__ unsigned short f2bf(float f) {
    unsigned u = __float_as_uint(f);
    u += 0x7FFF + ((u >> 16) & 1);
    return (unsigned short)(u >> 16);
}

__global__ __launch_bounds__(256)
void f32_to_bf16_k(const float* __restrict__ in, unsigned short* __restrict__ out, int n4) {
    int i = blockIdx.x * blockDim.x + threadIdx.x;
    int stride = gridDim.x * blockDim.x;
    for (; i < n4; i += stride) {
        float4 v = reinterpret_cast<const float4*>(in)[i];
        ushort4 o;
        o.x = f2bf(v.x); o.y = f2bf(v.y); o.z = f2bf(v.z); o.w = f2bf(v.w);
        reinterpret_cast<ushort4*>(out)[i] = o;
    }
}

__global__ __launch_bounds__(256)
void w_convert_k(const float* __restrict__ Wq, const float* __restrict__ Wk,
                 const float* __restrict__ Wv, unsigned short* __restrict__ out, int n4) {
    const float* src = blockIdx.y == 0 ? Wq : (blockIdx.y == 1 ? Wk : Wv);
    unsigned short* dst = out + (size_t)blockIdx.y * n4 * 4;
    int i = blockIdx.x * blockDim.x + threadIdx.x;
    int stride = gridDim.x * blockDim.x;
    for (; i < n4; i += stride) {
        float4 v = reinterpret_cast<const float4*>(src)[i];
        ushort4 o;
        o.x = f2bf(v.x); o.y = f2bf(v.y); o.z = f2bf(v.z); o.w = f2bf(v.w);
        reinterpret_cast<ushort4*>(dst)[i] = o;
    }
}

__device__ __forceinline__ void gload16(const unsigned short* g, unsigned short* l) {
    __builtin_amdgcn_global_load_lds(
        (const __attribute__((address_space(1))) unsigned int*)g,
        (__attribute__((address_space(3))) unsigned int*)l, 16, 0, 0);
}

// ============ NT GEMM core: BK=64, counted-vmcnt double buffer, XOR swizzle ============
// 128x128 tile, 256 threads (4 waves 2x2), LDS 64KB -> 2 blocks/CU.
// C[m,n] = scale * sum_k A[m,k]*B[n,k];  A:[M,K], B:[N,K] row-major bf16.
// LDS [rows][64]bf16; 16B chunk cc of row stored at chunk (cc ^ (row&7)): applied on the
// GLOBAL source address (LDS dest linear for global_load_lds) and on the ds_read address.
// vmcnt chain: each iter issues LPT=8 loads for tile t+1, waits vmcnt(8) -> tile t's loads
// (issued one full iteration earlier) drained; tile t+1's stay in flight.
// Block remap: bijective XCD chunking (m204) so contiguous work shares an XCD L2.
// TRIE: grid.x enumerates lower-triangle blocks (k = br*(br+1)/2 + bc), grid.y == 1.
template <int BM, int BN, int WM, int WN, typename CT, bool TRIE, bool KLIM>
__global__ __launch_bounds__(256, 2)
void gemm8(const unsigned short* __restrict__ A, const unsigned short* __restrict__ B,
           CT* __restrict__ C, int lda, int ldb, int ldc, int K,
           long long sA, long long sB, long long sC, float scale)
{
    constexpr int FM  = BM / WM / 16;            // 4
    constexpr int FN  = BN / WN / 16;            // 4
    constexpr int ACH = BM * 8;                  // A 16B-chunks per tile
    constexpr int LPT = (BM + BN) * 8 / 256;     // 8 loads/thread/tile

    // ---- bijective XCD-aware work remap (per z-slice) ----
    const int nbx = gridDim.x;
    const int nwg = nbx * gridDim.y;
    const int orig = blockIdx.y * nbx + blockIdx.x;
    const int q8 = nwg >> 3, r8 = nwg & 7;
    const int xcd = orig & 7, idx = orig >> 3;
    const int work = (xcd < r8 ? xcd * (q8 + 1) : r8 * (q8 + 1) + (xcd - r8) * q8) + idx;

    int br, bc;
    if constexpr (TRIE) {
        int rr = (int)((sqrtf(8.0f * (float)work + 1.0f) - 1.0f) * 0.5f);
        while ((rr + 1) * (rr + 2) / 2 <= work) ++rr;
        while (rr * (rr + 1) / 2 > work) --rr;
        br = rr; bc = work - rr * (rr + 1) / 2;   // bc <= br by construction
    } else {
        br = work / nbx; bc = work % nbx;
    }

    A += (long long)blockIdx.z * sA;
    B += (long long)blockIdx.z * sB;
    C += (long long)blockIdx.z * sC;

    int kmax = K;
    if (KLIM) { int kl = (br + 1) * BM; kmax = kl < K ? kl : K; }

    __shared__ unsigned short As[2][BM * 64];
    __shared__ unsigned short Bs[2][BN * 64];

    const int t    = threadIdx.x;
    const int lane = t & 63;
    const int wid  = t >> 6;
    const int wm   = wid / WN;
    const int wn   = wid % WN;
    const int m0   = br * BM, n0 = bc * BN;
    const int rsel = lane & 15;
    const int gsel = lane >> 4;                  // 0..3

    f32x4 acc[FM][FN];
#pragma unroll
    for (int m = 0; m < FM; ++m)
#pragma unroll
        for (int n = 0; n < FN; ++n) acc[m][n] = (f32x4){0.f, 0.f, 0.f, 0.f};

    auto stage = [&](int buf, int kt) {
        const int k0 = kt * 64;
#pragma unroll
        for (int i = 0; i < LPT; ++i) {
            int ci = i * 256 + t;
            if (ci < ACH) {
                int row = ci >> 3, cc = ci & 7;
                gload16(A + (long long)(m0 + row) * lda + k0 + ((cc ^ (row & 7)) * 8),
                        &As[buf][ci * 8]);
            } else {
                int cj = ci - ACH;
                int row = cj >> 3, cc = cj & 7;
                gload16(B + (long long)(n0 + row) * ldb + k0 + ((cc ^ (row & 7)) * 8),
                        &Bs[buf][cj * 8]);
            }
        }
    };

    const int nk = kmax >> 6;
    stage(0, 0);

    for (int kt = 0; kt < nk; ++kt) {
        const int c = kt & 1;
        // previous compute done -> safe to overwrite buf c^1
        __builtin_amdgcn_s_barrier();
        __builtin_amdgcn_sched_barrier(0);
        if (kt + 1 < nk) {
            stage(c ^ 1, kt + 1);                // tile t+1 loads stay in flight
            asm volatile("s_waitcnt vmcnt(8)" ::: "memory");  // tile t fully landed
        } else {
            asm volatile("s_waitcnt vmcnt(0)" ::: "memory");
        }
        __builtin_amdgcn_s_barrier();            // collective guarantee for buf c
        __builtin_amdgcn_sched_barrier(0);

        bf16x8 aF[FM][2], bF[FN][2];
#pragma unroll
        for (int m = 0; m < FM; ++m)
#pragma unroll
            for (int ks = 0; ks < 2; ++ks) {
                int r  = wm * (FM * 16) + m * 16 + rsel;
                int cc = ks * 4 + gsel;
                aF[m][ks] = *reinterpret_cast<const bf16x8*>(
                    &As[c][r * 64 + ((cc ^ (r & 7)) * 8)]);
            }
#pragma unroll
        for (int n = 0; n < FN; ++n)
#pragma unroll
            for (int ks = 0; ks < 2; ++ks) {
                int rb = wn * (FN * 16) + n * 16 + rsel;
                int cc = ks * 4 + gsel;
                bF[n][ks] = *reinterpret_cast<const bf16x8*>(
                    &Bs[c][rb * 64 + ((cc ^ (rb & 7)) * 8)]);
            }

        __builtin_amdgcn_s_setprio(1);
#pragma unroll
        for (int m = 0; m < FM; ++m)
#pragma unroll
            for (int n = 0; n < FN; ++n)
#pragma unroll
                for (int ks = 0; ks < 2; ++ks)
                    acc[m][n] = __builtin_amdgcn_mfma_f32_16x16x32_bf16(
                        aF[m][ks], bF[n][ks], acc[m][n], 0, 0, 0);
        __builtin_amdgcn_s_setprio(0);
    }

    // epilogue: D[row][col], col = lane&15, row = (lane>>4)*4 + i  (m89-verified)
    const int rowl = (lane >> 4) * 4;
#pragma unroll
    for (int m = 0; m < FM; ++m) {
#pragma unroll
        for (int n = 0; n < FN; ++n) {
#pragma unroll
            for (int i = 0; i < 4; ++i) {
                int r  = m0 + wm * (FM * 16) + m * 16 + rowl + i;
                int cI = n0 + wn * (FN * 16) + n * 16 + rsel;
                float v = acc[m][n][i] * scale;
                if constexpr (sizeof(CT) == 2)
                    ((unsigned short*)C)[(long long)r * ldc + cI] = f2bf(v);
                else
                    ((float*)C)[(long long)r * ldc + cI] = v;
            }
        }
    }
}

// ---- causal row softmax: 1 global read (LDS-cached), vectorized ----
__device__ __forceinline__ float waveMax(float v) {
#pragma unroll
    for (int o = 32; o > 0; o >>= 1) v = fmaxf(v, __shfl_xor(v, o, 64));
    return v;
}
__device__ __forceinline__ float waveSum(float v) {
#pragma unroll
    for (int o = 32; o > 0; o >>= 1) v += __shfl_xor(v, o, 64);
    return v;
}

__global__ __launch_bounds__(256)
void softmax_causal(const float* __restrict__ S, unsigned short* __restrict__ P, int Slen) {
    __shared__ float e[2048];
    __shared__ float red[4];
    long long row = blockIdx.x;                 // b*Slen + q
    int q = (int)(row % Slen);
    const float* srow = S + row * (long long)Slen;
    unsigned short* prow = P + row * (long long)Slen;
    int len = q + 1;
    int t = threadIdx.x;

    int nfull = len >> 2;
    float mx = -3.0e38f;
    for (int i = t; i < nfull; i += 256) {
        float4 v = reinterpret_cast<const float4*>(srow)[i];
        e[4 * i + 0] = v.x; e[4 * i + 1] = v.y;
        e[4 * i + 2] = v.z; e[4 * i + 3] = v.w;
        mx = fmaxf(fmaxf(fmaxf(mx, v.x), v.y), fmaxf(v.z, v.w));
    }
    if (t < (len & 3)) {
        float v = srow[nfull * 4 + t];
        e[nfull * 4 + t] = v;
        mx = fmaxf(mx, v);
    }
    mx = waveMax(mx);
    if ((t & 63) == 0) red[t >> 6] = mx;
    __syncthreads();
    mx = fmaxf(fmaxf(red[0], red[1]), fmaxf(red[2], red[3]));

    float sum = 0.f;
    for (int k = t; k < len; k += 256) {
        float v = __expf(e[k] - mx);
        e[k] = v;
        sum += v;
    }
    sum = waveSum(sum);
    __syncthreads();
    if ((t & 63) == 0) red[t >> 6] = sum;
    __syncthreads();
    sum = red[0] + red[1] + red[2] + red[3];
    float inv = 1.0f / sum;

    int wlim = ((q >> 7) + 1) << 7;             // PV (BM=128) reads only k < roundup(len,128)
    __syncthreads();                            // e[] writes visible
    for (int i = t; i < (wlim >> 2); i += 256) {
        int k = 4 * i;
        ushort4 o;
        o.x = (k + 0 < len) ? f2bf(e[k + 0] * inv) : (unsigned short)0;
        o.y = (k + 1 < len) ? f2bf(e[k + 1] * inv) : (unsigned short)0;
        o.z = (k + 2 < len) ? f2bf(e[k + 2] * inv) : (unsigned short)0;
        o.w = (k + 3 < len) ? f2bf(e[k + 3] * inv) : (unsigned short)0;
        reinterpret_cast<ushort4*>(prow)[i] = o;
    }
}

extern "C" void kernel_launch(void* const* d_in, const int* in_sizes, int n_in,
                              void* d_out, int out_size, void* d_ws, size_t ws_size,
                              hipStream_t stream) {
    const int B = 4, S = 2048, D = 1024;
    const float* X  = (const float*)d_in[0];
    const float* Wq = (const float*)d_in[1];
    const float* Wk = (const float*)d_in[2];
    const float* Wv = (const float*)d_in[3];
    float* out = (float*)d_out;

    char* ws = (char*)d_ws;
    unsigned short* Xb  = (unsigned short*)ws; ws += (size_t)B * S * D * 2;
    unsigned short* Wqb = (unsigned short*)ws; ws += (size_t)D * D * 2;  // Wq,Wk,Wv contiguous
    unsigned short* Wkb = (unsigned short*)ws; ws += (size_t)D * D * 2;
    unsigned short* Wvb = (unsigned short*)ws; ws += (size_t)D * D * 2;
    unsigned short* Qb  = (unsigned short*)ws; ws += (size_t)B * S * D * 2;  // Q,K contiguous
    unsigned short* Kb  = (unsigned short*)ws; ws += (size_t)B * S * D * 2;
    unsigned short* Vt  = (unsigned short*)ws; ws += (size_t)B * S * D * 2;  // [b][e][k]
    float*          Sc  = (float*)ws;          ws += (size_t)B * S * S * 4;
    unsigned short* P   = (unsigned short*)ws; ws += (size_t)B * S * S * 2;

    f32_to_bf16_k<<<2048, 256, 0, stream>>>(X, Xb, B * S * D / 4);
    w_convert_k<<<dim3(512, 3), 256, 0, stream>>>(Wq, Wk, Wv, Wqb, D * D / 4);

    dim3 blk(256);
    // Q and K in one dispatch: 128x128 tiles, grid (8, 64, 2), XCD-chunked
    gemm8<128, 128, 2, 2, unsigned short, false, false>
        <<<dim3(D / 128, B * S / 128, 2), blk, 0, stream>>>(
        Xb, Wqb, Qb, D, D, D, D, 0, (long long)D * D, (long long)B * S * D, 1.0f);

    // Vt[b] = Wv @ Xb[b]^T : grid (16, 8, 4) = 512 blocks
    gemm8<128, 128, 2, 2, unsigned short, false, false>
        <<<dim3(S / 128, D / 128, B), blk, 0, stream>>>(
        Wvb, Xb, Vt, D, D, S, D, 0, (long long)S * D, (long long)D * S, 1.0f);

    // scores = (Q K^T)/32: triangular enumeration, 136 blocks/batch, fp32
    const int nbt = (S / 128) * (S / 128 + 1) / 2;   // 136
    gemm8<128, 128, 2, 2, float, true, false>
        <<<dim3(nbt, 1, B), blk, 0, stream>>>(
        Qb, Kb, Sc, D, D, S, D, (long long)S * D, (long long)S * D, (long long)S * S, 0.03125f);

    softmax_causal<<<B * S, 256, 0, stream>>>(Sc, P, S);

    // out = P @ Vt^T : grid (8, 16, 4) = 512 blocks, KLIM
    gemm8<128, 128, 2, 2, float, false, true>
        <<<dim3(D / 128, S / 128, B), blk, 0, stream>>>(
        P, Vt, out, S, S, D, S, (long long)S * S, (long long)D * S, (long long)S * D, 1.0f);
}